// Round 1
// 1737.820 us; speedup vs baseline: 1.7622x; 1.7622x over previous
//
#include <hip/hip_runtime.h>
#include <hip/hip_bf16.h>

// ---------------- problem constants ----------------
#define NU      50000
#define NT      100000
#define NPADR   100032         // 1563*64
#define NC      5
#define DD      64
#define AA      32
#define EE      1600000
#define CE      (NC*EE)        // 8,000,000
#define CN      (NC*NT)        // 500,000
#define ROWF    (NC*DD)        // 320
#define NBL     1563
#define OUT_ELEMS 32000000     // NT*ROWF

// ---------------- workspace layout (bytes) ----------------
#define TMP_OFF   0            // bf16 spmm out: NPADR*320*2 = 64,020,480
#define XB_OFF    64020480     // bf16 x rows:   64,020,480
#define EB_OFF    128040960    // packed edges:  32,000,000
#define OFF_OFF   160040960    // offs: (CN+1)*4
#define CNT_OFF   162040964    // counts: CN*4
#define RANK_OFF  164040964    // rank: CE*4 = 32,000,000
#define CRI1_OFF  196040964    // 1280
#define BSUM_OFF  196042244    // 977*4
#define WC_OFF    196046160    // bf16 Wc B-fragments: 2*5*8*64*16 = 81,920
#define W1B_OFF   196128080    // bf16 W1 B-fragments: 5*4*64*16   = 20,480

using short8 = __attribute__((ext_vector_type(8))) short;
using f32x4  = __attribute__((ext_vector_type(4))) float;

__device__ __forceinline__ f32x4 mfma16(short8 a, short8 b, f32x4 c){
  return __builtin_amdgcn_mfma_f32_16x16x32_bf16(a, b, c, 0, 0, 0);
}
__device__ __forceinline__ float lk(float x){ return x >= 0.f ? x : 0.3f*x; }
__device__ __forceinline__ float fast_tanh(float x){
  float e = __expf(2.0f*x);
  return (e - 1.0f) * __builtin_amdgcn_rcpf(e + 1.0f);
}
__device__ __forceinline__ float bf2f(unsigned u){ return __uint_as_float(u << 16); }
__device__ __forceinline__ unsigned short f2bf_rn(float f){
  unsigned b = __float_as_uint(f);
  return (unsigned short)((b + 0x7FFFu + ((b >> 16) & 1u)) >> 16);
}

// ---------- input fp32 -> bf16 x rows ----------
__global__ __launch_bounds__(256) void dmcr_cvt(const float* __restrict__ ue,
                                                const float* __restrict__ ie,
                                                unsigned short* __restrict__ xb){
  size_t idx = ((size_t)blockIdx.x*256 + threadIdx.x) * 4;   // 31250 blocks, exact
  const float* src = (idx < (size_t)NU*ROWF) ? (ue + idx) : (ie + (idx - (size_t)NU*ROWF));
  float4 f = *(const float4*)src;
  ushort4 h;
  h.x = f2bf_rn(f.x); h.y = f2bf_rn(f.y); h.z = f2bf_rn(f.z); h.w = f2bf_rn(f.w);
  *(ushort4*)(xb + idx) = h;
}

// ---------- CSR build: histogram + per-edge rank ----------
__global__ __launch_bounds__(256) void dmcr_count(const int* __restrict__ rows,
                                                  unsigned* __restrict__ counts,
                                                  unsigned* __restrict__ rank){
  const int c = blockIdx.y;
  const size_t g = (size_t)c*EE + blockIdx.x*256 + threadIdx.x;
  const int r = rows[g];
  rank[g] = atomicAdd(&counts[c*NT + r], 1u);
}

// ---------- 3-kernel exclusive scan over CN counters ----------
#define SCAN_NB 977
__global__ __launch_bounds__(512) void dmcr_scan1(const unsigned* __restrict__ counts,
                                                  unsigned* __restrict__ offs,
                                                  unsigned* __restrict__ bsum){
  __shared__ unsigned sh[512];
  const int t = threadIdx.x; const int idx = blockIdx.x*512 + t;
  unsigned v = (idx < CN) ? counts[idx] : 0u;
  sh[t] = v; __syncthreads();
  for (int off=1; off<512; off<<=1){
    unsigned x = (t>=off) ? sh[t-off] : 0u; __syncthreads();
    sh[t] += x; __syncthreads();
  }
  if (idx < CN) offs[idx] = sh[t] - v;
  if (t == 511) bsum[blockIdx.x] = sh[511];
}
__global__ __launch_bounds__(1024) void dmcr_scan2(unsigned* __restrict__ bsum,
                                                   unsigned* __restrict__ offs){
  __shared__ unsigned sh[1024];
  const int t = threadIdx.x;
  unsigned v = (t < SCAN_NB) ? bsum[t] : 0u;
  sh[t] = v; __syncthreads();
  for (int off=1; off<1024; off<<=1){
    unsigned x = (t>=off) ? sh[t-off] : 0u; __syncthreads();
    sh[t] += x; __syncthreads();
  }
  if (t < SCAN_NB) bsum[t] = sh[t] - v;
  if (t == 0) offs[CN] = (unsigned)CE;
}
__global__ __launch_bounds__(512) void dmcr_scan3(unsigned* __restrict__ offs,
                                                  const unsigned* __restrict__ bsum){
  const int idx = blockIdx.x*512 + threadIdx.x;
  if (idx < CN) offs[idx] += bsum[blockIdx.x];
}

// ---------- scatter packed 4B edges: (col<<15)|q15, atomic-free ----------
__global__ __launch_bounds__(256) void dmcr_scatter(const int* __restrict__ rows,
                                                    const int* __restrict__ cols,
                                                    const float* __restrict__ vals,
                                                    const unsigned* __restrict__ offs,
                                                    const unsigned* __restrict__ rank,
                                                    unsigned* __restrict__ eb4){
  const int c = blockIdx.y;
  const size_t g = (size_t)c*EE + blockIdx.x*256 + threadIdx.x;
  const int r = rows[g];
  unsigned slot = offs[c*NT + r] + rank[g];
  unsigned q = (unsigned)(vals[g] * 3276700.0f + 0.5f);     // round(val/0.01*32767)
  q = q > 32767u ? 32767u : q;
  eb4[slot] = (((unsigned)cols[g]) << 15) | q;
}

// ---------- cri chain + cri_mean + zero item-pad row ----------
__global__ __launch_bounds__(320) void dmcr_cri(const float* __restrict__ cri0,
                                                const float* __restrict__ Wrel,
                                                float* __restrict__ cri1_ws,
                                                float* __restrict__ outp){
  __shared__ float s0[320], s1[320];
  const int t = threadIdx.x; const int c = t>>6, d = t&63;
  float v0 = cri0[t];
  s0[t] = v0; __syncthreads();
  float a = 0.f;
  #pragma unroll
  for (int k=0;k<DD;k++) a += s0[c*DD+k] * Wrel[k*DD + d];
  float v1 = lk(a); s1[t] = v1; cri1_ws[t] = v1; __syncthreads();
  float b = 0.f;
  #pragma unroll
  for (int k=0;k<DD;k++) b += s1[c*DD+k] * Wrel[DD*DD + k*DD + d];
  float v2 = lk(b);
  outp[OUT_ELEMS + 320 + t] = (v0 + v1 + v2) * (1.f/3.f);   // cri_mean
  outp[OUT_ELEMS + t] = 0.f;                                // items zero row
}

// ---------- Wc[l][c] = w_gcn * diag(cri_l[c]) * W_gc[l], packed as bf16 MFMA B-frags ----------
// frag f = nt*2+kh (nt=0..3 over d-cols, kh=0..1 over k-halves); lane l holds
// B[k = kh*32 + 8*(l>>4) + j][n = nt*16 + (l&15)], j=0..7, as 8 bf16 (16 B).
__global__ __launch_bounds__(64) void dmcr_wc(const float* __restrict__ cri0,
                                              const float* __restrict__ cri1,
                                              const float* __restrict__ wgcn,
                                              const float* __restrict__ Wgc,
                                              unsigned short* __restrict__ WcB){
  __shared__ float wcl[64][65];
  const int b = blockIdx.x; const int l = b/5, c = b%5; const int j = threadIdx.x;
  const float* cri = (l==0 ? cri0 : cri1) + c*DD;
  float tt[DD];
  #pragma unroll
  for (int d=0; d<DD; d++) tt[d] = cri[d] * Wgc[l*DD*DD + d*DD + j];
  for (int i=0; i<DD; i++){
    float a = 0.f;
    #pragma unroll
    for (int d=0; d<DD; d++) a += wgcn[i*DD+d] * tt[d];
    wcl[i][j] = a;                       // wcl[k][d]
  }
  __syncthreads();
  const int l15 = j&15, lg = j>>4;
  #pragma unroll
  for (int f=0; f<8; f++){
    const int nt = f>>1, kh = f&1;
    unsigned pk0, pk1, pk2, pk3;
    {
      unsigned short h0 = f2bf_rn(wcl[kh*32 + lg*8 + 0][nt*16 + l15]);
      unsigned short h1 = f2bf_rn(wcl[kh*32 + lg*8 + 1][nt*16 + l15]);
      pk0 = (unsigned)h0 | ((unsigned)h1 << 16);
      h0 = f2bf_rn(wcl[kh*32 + lg*8 + 2][nt*16 + l15]);
      h1 = f2bf_rn(wcl[kh*32 + lg*8 + 3][nt*16 + l15]);
      pk1 = (unsigned)h0 | ((unsigned)h1 << 16);
      h0 = f2bf_rn(wcl[kh*32 + lg*8 + 4][nt*16 + l15]);
      h1 = f2bf_rn(wcl[kh*32 + lg*8 + 5][nt*16 + l15]);
      pk2 = (unsigned)h0 | ((unsigned)h1 << 16);
      h0 = f2bf_rn(wcl[kh*32 + lg*8 + 6][nt*16 + l15]);
      h1 = f2bf_rn(wcl[kh*32 + lg*8 + 7][nt*16 + l15]);
      pk3 = (unsigned)h0 | ((unsigned)h1 << 16);
    }
    uint4 u; u.x=pk0; u.y=pk1; u.z=pk2; u.w=pk3;
    *(uint4*)(WcB + ((size_t)(b*8 + f)*64 + j)*8) = u;
  }
}

// ---------- W1[i] (64x32) packed as bf16 MFMA B-frags: f = nt*2+kh, nt=0..1 ----------
__global__ __launch_bounds__(64) void dmcr_w1b(const float* __restrict__ W1,
                                               unsigned short* __restrict__ W1B){
  __shared__ float wl[64][33];
  const int i = blockIdx.x; const int tdx = threadIdx.x;
  for (int r=0; r<32; r++){
    int e = r*64 + tdx;
    wl[e>>5][e&31] = W1[i*DD*AA + e];    // wl[d][a]
  }
  __syncthreads();
  const int l15 = tdx&15, lg = tdx>>4;
  #pragma unroll
  for (int f=0; f<4; f++){
    const int nt = f>>1, kh = f&1;
    unsigned pk0, pk1, pk2, pk3;
    {
      unsigned short h0 = f2bf_rn(wl[kh*32 + lg*8 + 0][nt*16 + l15]);
      unsigned short h1 = f2bf_rn(wl[kh*32 + lg*8 + 1][nt*16 + l15]);
      pk0 = (unsigned)h0 | ((unsigned)h1 << 16);
      h0 = f2bf_rn(wl[kh*32 + lg*8 + 2][nt*16 + l15]);
      h1 = f2bf_rn(wl[kh*32 + lg*8 + 3][nt*16 + l15]);
      pk1 = (unsigned)h0 | ((unsigned)h1 << 16);
      h0 = f2bf_rn(wl[kh*32 + lg*8 + 4][nt*16 + l15]);
      h1 = f2bf_rn(wl[kh*32 + lg*8 + 5][nt*16 + l15]);
      pk2 = (unsigned)h0 | ((unsigned)h1 << 16);
      h0 = f2bf_rn(wl[kh*32 + lg*8 + 6][nt*16 + l15]);
      h1 = f2bf_rn(wl[kh*32 + lg*8 + 7][nt*16 + l15]);
      pk3 = (unsigned)h0 | ((unsigned)h1 << 16);
    }
    uint4 u; u.x=pk0; u.y=pk1; u.z=pk2; u.w=pk3;
    *(uint4*)(W1B + ((size_t)(i*4 + f)*64 + tdx)*8) = u;
  }
}

// ---------- gather-SpMM (bf16 x, bf16 out) ----------
__global__ __launch_bounds__(256) void dmcr_spmm(const unsigned* __restrict__ offs,
                                                 const unsigned* __restrict__ eb4,
                                                 const unsigned short* __restrict__ xb,
                                                 unsigned short* __restrict__ tmp16){
  const int c = blockIdx.y;
  const int w = __builtin_amdgcn_readfirstlane(threadIdx.x >> 6);
  const int r = blockIdx.x*4 + w;
  const int d = threadIdx.x & 63;
  const int oi = c*NT + r;
  const int co = c*DD + d;
  unsigned beg = offs[oi], end = offs[oi+1];
  float acc = 0.f;
  unsigned e = beg;
  for (; e+2 <= end; e += 2){
    unsigned p0 = eb4[e], p1 = eb4[e+1];
    float v0 = (float)(p0 & 0x7FFFu) * (0.01f/32767.f);
    float v1 = (float)(p1 & 0x7FFFu) * (0.01f/32767.f);
    float x0 = bf2f(xb[(size_t)(p0 >> 15)*ROWF + co]);
    float x1 = bf2f(xb[(size_t)(p1 >> 15)*ROWF + co]);
    acc = fmaf(v0, x0, acc);
    acc = fmaf(v1, x1, acc);
  }
  if (e < end){
    unsigned p0 = eb4[e];
    float v0 = (float)(p0 & 0x7FFFu) * (0.01f/32767.f);
    float x0 = bf2f(xb[(size_t)(p0 >> 15)*ROWF + co]);
    acc = fmaf(v0, x0, acc);
  }
  tmp16[(size_t)r*ROWF + co] = f2bf_rn(acc);
}

// ---------- fused layer (MFMA): emb=tile@Wc -> leaky -> s=tanh(emb@W1)W2 -> softmax -> mix ----------
// block = 320 threads (5 waves, wave w = criterion c for ph1-2, = output channel i for ph3).
// tile = 64 nodes. LDS stride 328 elems (656 B = 41*16 B: 16B-aligned rows, ~2-way bank alias).
#define SHS 328
__global__ __launch_bounds__(320, 4) void dmcr_layer(const unsigned short* __restrict__ tmp16,
                                                     const unsigned short* __restrict__ WcB,
                                                     const unsigned short* __restrict__ W1B,
                                                     const float* __restrict__ W2,
                                                     float* __restrict__ outp,
                                                     unsigned short* __restrict__ xb,
                                                     const float* __restrict__ ue,
                                                     const float* __restrict__ ie,
                                                     int layer){
  __shared__ unsigned short sh16[64*SHS];    // 41,984 B
  __shared__ float sx[1600];                 //  6,400 B  [i][c][n]
  const int t = threadIdx.x;
  const int w = __builtin_amdgcn_readfirstlane(t >> 6);
  const int lane = t & 63;
  const int l15 = lane & 15, lg = lane >> 4;
  const size_t base = (size_t)blockIdx.x * (64*ROWF);

  // ---- Wc B-fragments (issue early; global latency hides under staging) ----
  short8 wcf[8];
  {
    const uint4* wp = (const uint4*)WcB + ((size_t)(layer*NC + w)*8)*64 + lane;
    #pragma unroll
    for (int f=0; f<8; f++){ uint4 u = wp[(size_t)f*64]; wcf[f] = *(short8*)&u; }
  }

  // ---- phase 0: coalesced stage of tile (16B-aligned now) ----
  #pragma unroll
  for (int j = 0; j < 8; j++){
    int e = j*2560 + t*8;                    // 8 consecutive elems, within one row
    uint4 pk = *(const uint4*)(tmp16 + base + e);
    int n = e / ROWF, q = e % ROWF;
    *(uint4*)(sh16 + n*SHS + q) = pk;
  }
  __syncthreads();

  // ---- phase 1: emb(64x64) = tile[:, w*64:+64] @ Wc[layer][w]  (32 MFMAs) ----
  f32x4 c1[4][4];
  #pragma unroll
  for (int mt=0;mt<4;mt++)
    #pragma unroll
    for (int nt=0;nt<4;nt++) c1[mt][nt] = (f32x4){0.f,0.f,0.f,0.f};
  #pragma unroll
  for (int kh=0; kh<2; kh++)
    #pragma unroll
    for (int mt=0; mt<4; mt++){
      short8 a = *(const short8*)(sh16 + (mt*16+l15)*SHS + w*DD + kh*32 + lg*8);
      #pragma unroll
      for (int nt=0; nt<4; nt++) c1[mt][nt] = mfma16(a, wcf[nt*2+kh], c1[mt][nt]);
    }
  // leaky + write emb back (own c-columns only: no cross-wave hazard)
  #pragma unroll
  for (int mt=0;mt<4;mt++)
    #pragma unroll
    for (int nt=0;nt<4;nt++)
      #pragma unroll
      for (int r=0;r<4;r++)
        sh16[(mt*16 + lg*4 + r)*SHS + w*DD + nt*16 + l15] = f2bf_rn(lk(c1[mt][nt][r]));

  // ---- phase 2: s[n,i,c=w] = sum_a tanh(emb @ W1[i]) * W2[i]  (16 MFMAs/i) ----
  short8 ea[2][4];
  #pragma unroll
  for (int kh=0;kh<2;kh++)
    #pragma unroll
    for (int mt=0;mt<4;mt++)
      ea[kh][mt] = *(const short8*)(sh16 + (mt*16+l15)*SHS + w*DD + kh*32 + lg*8);

  #pragma unroll 1
  for (int i=0;i<5;i++){
    short8 w1f[4];
    {
      const uint4* wp = (const uint4*)W1B + (size_t)(i*4)*64 + lane;
      #pragma unroll
      for (int f=0; f<4; f++){ uint4 u = wp[(size_t)f*64]; w1f[f] = *(short8*)&u; }
    }
    float w2a = W2[i*AA + l15];
    float w2b = W2[i*AA + 16 + l15];
    f32x4 c2[4][2];
    #pragma unroll
    for (int mt=0;mt<4;mt++){ c2[mt][0]=(f32x4){0.f,0.f,0.f,0.f}; c2[mt][1]=(f32x4){0.f,0.f,0.f,0.f}; }
    #pragma unroll
    for (int kh=0;kh<2;kh++)
      #pragma unroll
      for (int mt=0;mt<4;mt++){
        c2[mt][0] = mfma16(ea[kh][mt], w1f[0+kh], c2[mt][0]);
        c2[mt][1] = mfma16(ea[kh][mt], w1f[2+kh], c2[mt][1]);
      }
    // tanh, x W2, butterfly-reduce over a (lane&15 axis + the two n-tiles)
    #pragma unroll
    for (int mt=0;mt<4;mt++){
      float vr[4];
      #pragma unroll
      for (int r=0;r<4;r++){
        float v = fast_tanh(c2[mt][0][r])*w2a + fast_tanh(c2[mt][1][r])*w2b;
        v += __shfl_xor(v,1); v += __shfl_xor(v,2); v += __shfl_xor(v,4); v += __shfl_xor(v,8);
        vr[r] = v;
      }
      int rr = lane & 3;
      float vs = (rr==0) ? vr[0] : (rr==1) ? vr[1] : (rr==2) ? vr[2] : vr[3];
      if (l15 < 4) sx[i*320 + w*64 + mt*16 + lg*4 + rr] = vs;
    }
  }
  __syncthreads();

  // ---- phase 3: softmax over c (wave = i) + mix pre = leaky(attn @ emb) ----
  float acc[64];
  {
    float sv[5];
    #pragma unroll
    for (int c = 0; c < 5; c++) sv[c] = sx[w*320 + c*64 + lane];
    float m = fmaxf(fmaxf(fmaxf(sv[0],sv[1]),fmaxf(sv[2],sv[3])),sv[4]);
    float at[5]; float ssum = 0.f;
    #pragma unroll
    for (int c = 0; c < 5; c++){ at[c] = __expf(sv[c]-m); ssum += at[c]; }
    float inv = __builtin_amdgcn_rcpf(ssum);
    #pragma unroll
    for (int d = 0; d < 64; d++) acc[d] = 0.f;
    #pragma unroll 1
    for (int c = 0; c < 5; c++){
      float a = at[c] * inv;
      const uint4* src = (const uint4*)(sh16 + lane*SHS + c*DD);
      #pragma unroll
      for (int g = 0; g < 8; g++){
        uint4 pk = src[g];
        acc[g*8+0] = fmaf(a, __uint_as_float(pk.x << 16),        acc[g*8+0]);
        acc[g*8+1] = fmaf(a, __uint_as_float(pk.x & 0xffff0000u), acc[g*8+1]);
        acc[g*8+2] = fmaf(a, __uint_as_float(pk.y << 16),        acc[g*8+2]);
        acc[g*8+3] = fmaf(a, __uint_as_float(pk.y & 0xffff0000u), acc[g*8+3]);
        acc[g*8+4] = fmaf(a, __uint_as_float(pk.z << 16),        acc[g*8+4]);
        acc[g*8+5] = fmaf(a, __uint_as_float(pk.z & 0xffff0000u), acc[g*8+5]);
        acc[g*8+6] = fmaf(a, __uint_as_float(pk.w << 16),        acc[g*8+6]);
        acc[g*8+7] = fmaf(a, __uint_as_float(pk.w & 0xffff0000u), acc[g*8+7]);
      }
    }
    #pragma unroll
    for (int d = 0; d < 64; d++) acc[d] = lk(acc[d]);
  }
  __syncthreads();                            // everyone done reading emb
  {
    unsigned short* shr = sh16 + lane*SHS + w*DD;
    #pragma unroll
    for (int d = 0; d < 64; d++) shr[d] = f2bf_rn(acc[d]);
  }
  __syncthreads();

  // ---- phase 5: coalesced copy-out (+final combine) ----
  #pragma unroll
  for (int j = 0; j < 8; j++){
    int e = j*2560 + t*8;
    size_t gidx = base + e;
    if (gidx >= (size_t)OUT_ELEMS) continue;  // last tile guard (pad nodes)
    int n = e / ROWF, q = e % ROWF;
    uint4 pk = *(const uint4*)(sh16 + n*SHS + q);
    float v[8];
    v[0]=__uint_as_float(pk.x<<16); v[1]=__uint_as_float(pk.x&0xffff0000u);
    v[2]=__uint_as_float(pk.y<<16); v[3]=__uint_as_float(pk.y&0xffff0000u);
    v[4]=__uint_as_float(pk.z<<16); v[5]=__uint_as_float(pk.z&0xffff0000u);
    v[6]=__uint_as_float(pk.w<<16); v[7]=__uint_as_float(pk.w&0xffff0000u);
    if (layer == 1){
      const float* p0 = (gidx < (size_t)NU*ROWF) ? (ue + gidx) : (ie + (gidx - (size_t)NU*ROWF));
      #pragma unroll
      for (int r = 0; r < 8; r += 4){
        float4 a0 = *(const float4*)(p0 + r);
        float4 o0 = *(const float4*)(outp + gidx + r);
        float4 ov;
        ov.x = (v[r+0] + a0.x + o0.x) * (1.f/3.f);
        ov.y = (v[r+1] + a0.y + o0.y) * (1.f/3.f);
        ov.z = (v[r+2] + a0.z + o0.z) * (1.f/3.f);
        ov.w = (v[r+3] + a0.w + o0.w) * (1.f/3.f);
        *(float4*)(outp + gidx + r) = ov;
      }
    } else {
      #pragma unroll
      for (int r = 0; r < 8; r += 4){
        float4 ov; ov.x = v[r+0]; ov.y = v[r+1]; ov.z = v[r+2]; ov.w = v[r+3];
        *(float4*)(outp + gidx + r) = ov;
      }
      *(uint4*)(xb + gidx) = pk;              // identical bf16 bits
    }
  }
}

extern "C" void kernel_launch(void* const* d_in, const int* in_sizes, int n_in,
                              void* d_out, int out_size, void* d_ws, size_t ws_size,
                              hipStream_t stream) {
  const int*   rows = (const int*)  d_in[0];
  const int*   cols = (const int*)  d_in[1];
  const float* vals = (const float*)d_in[2];
  const float* ue   = (const float*)d_in[3];
  const float* ie   = (const float*)d_in[4];
  const float* cri0 = (const float*)d_in[5];
  const float* wgcn = (const float*)d_in[6];
  const float* Wgc  = (const float*)d_in[7];
  const float* Wrel = (const float*)d_in[8];
  const float* W1   = (const float*)d_in[9];
  const float* W2   = (const float*)d_in[10];
  float* outp = (float*)d_out;
  char*  ws   = (char*)d_ws;

  unsigned short* tmp16 = (unsigned short*)(ws + TMP_OFF);
  unsigned short* xb    = (unsigned short*)(ws + XB_OFF);
  unsigned*       eb4   = (unsigned*)      (ws + EB_OFF);
  unsigned*       offs  = (unsigned*)      (ws + OFF_OFF);
  unsigned*       counts= (unsigned*)      (ws + CNT_OFF);
  unsigned*       rank  = (unsigned*)      (ws + RANK_OFF);
  float*          cri1  = (float*)         (ws + CRI1_OFF);
  unsigned*       bsum  = (unsigned*)      (ws + BSUM_OFF);
  unsigned short* WcB   = (unsigned short*)(ws + WC_OFF);
  unsigned short* W1B   = (unsigned short*)(ws + W1B_OFF);

  // CSR build (reused by both layers)
  hipMemsetAsync(counts, 0, CN*sizeof(unsigned), stream);
  dmcr_cvt    <<<31250, 256, 0, stream>>>(ue, ie, xb);
  dmcr_count  <<<dim3(EE/256, NC), 256, 0, stream>>>(rows, counts, rank);
  dmcr_scan1  <<<SCAN_NB, 512, 0, stream>>>(counts, offs, bsum);
  dmcr_scan2  <<<1, 1024, 0, stream>>>(bsum, offs);
  dmcr_scan3  <<<SCAN_NB, 512, 0, stream>>>(offs, bsum);
  dmcr_scatter<<<dim3(EE/256, NC), 256, 0, stream>>>(rows, cols, vals, offs, rank, eb4);

  // tiny precomputes
  dmcr_cri<<<1, 320, 0, stream>>>(cri0, Wrel, cri1, outp);
  dmcr_wc <<<10, 64, 0, stream>>>(cri0, cri1, wgcn, Wgc, WcB);
  dmcr_w1b<<<5, 64, 0, stream>>>(W1, W1B);

  // layer 1: x = bf16(concat(ue,ie)); writes pre1 -> outp (fp32) and xb (bf16)
  dmcr_spmm <<<dim3(NT/4, NC), 256, 0, stream>>>(offs, eb4, xb, tmp16);
  dmcr_layer<<<NBL, 320, 0, stream>>>(tmp16, WcB, W1B, W2, outp, xb, ue, ie, 0);

  // layer 2: x = bf16(pre1); out = (pre0 + pre1 + pre2)/3
  dmcr_spmm <<<dim3(NT/4, NC), 256, 0, stream>>>(offs, eb4, xb, tmp16);
  dmcr_layer<<<NBL, 320, 0, stream>>>(tmp16, WcB, W1B, W2, outp, xb, ue, ie, 1);
}